// Round 3
// baseline (858.303 us; speedup 1.0000x reference)
//
#include <hip/hip_runtime.h>

typedef __bf16 bf16x8 __attribute__((ext_vector_type(8)));
typedef __bf16 bf16x4 __attribute__((ext_vector_type(4)));
typedef float  f32x4  __attribute__((ext_vector_type(4)));

#define D_DIM 9984   // 13*768
#define H1P   1024   // H1=1000 padded
#define M_DIM 8192   // B*S
#define KH    4992   // K half (split-K 2-way), 156*32
#define ITERS 156

__device__ __forceinline__ void gld_lds16(const void* g, void* l) {
  __builtin_amdgcn_global_load_lds((__attribute__((address_space(1))) void*)(g),
                                   (__attribute__((address_space(3))) void*)(l),
                                   16, 0, 0);
}

// ---- W1 [9984][1000] fp32 -> W1T [1024][9984] bf16 (rows >=1000 zeroed) ----
__global__ __launch_bounds__(256) void k_transpose_w1(const float* __restrict__ W1,
                                                      __bf16* __restrict__ W1T) {
  __shared__ float tile[32][33];
  const int bk = blockIdx.x, bn = blockIdx.y;
  const int tx = threadIdx.x, ty = threadIdx.y;
#pragma unroll
  for (int i = 0; i < 4; ++i) {
    const int kk = bk * 32 + ty + i * 8;
    const int nn = bn * 32 + tx;
    tile[ty + i * 8][tx] = (nn < 1000) ? W1[(size_t)kk * 1000 + nn] : 0.f;
  }
  __syncthreads();
#pragma unroll
  for (int i = 0; i < 4; ++i) {
    const int nn = bn * 32 + ty + i * 8;   // row of W1T (n)
    const int kk = bk * 32 + tx;           // col of W1T (k)
    W1T[(size_t)nn * D_DIM + kk] = (__bf16)tile[tx][ty + i * 8];
  }
}

// ---- W2 [1000][40] fp32 -> W2T [64][1024] bf16 (pads zeroed) ----
__global__ void k_prep_w2(const float* __restrict__ W2, __bf16* __restrict__ W2T) {
  const int idx = blockIdx.x * 256 + threadIdx.x;  // 65536 total
  const int j = idx >> 10, k = idx & 1023;
  const float v = (j < 40 && k < 1000) ? W2[k * 40 + j] : 0.f;
  W2T[idx] = (__bf16)v;
}

// ---- GEMM1 split-K: Cp[kh] = A[:, khalf] @ W1[khalf, :]  (fp32 partials) ----
// 128x128 tile, BK=32, 4 waves 2x2, 4x4 frags. grid (64,8,2) -> 4 blocks/CU.
// A: fp32 global -> regs (prefetch) -> cvt -> ds_write_b128 into padded As.
// B: W1T bf16 via global_load_lds width 16.
__global__ __launch_bounds__(256) void k_gemm1s(const float* __restrict__ A,
                                                const __bf16* __restrict__ BT,
                                                float* __restrict__ Cp) {
  __shared__ __bf16 As[128 * 40];   // row stride 40 (padded: conflict-free reads)
  __shared__ __bf16 Bs[128 * 32];
  const int tid  = threadIdx.x;
  const int lane = tid & 63;
  const int wid  = tid >> 6;
  const int tm = blockIdx.x, tn = blockIdx.y, kh = blockIdx.z;
  const int wm = wid & 1, wn = wid >> 1;

  // A staging: thread -> row = tid/2, 16-float half = tid%2
  const int arow = tid >> 1;
  const int ahalf = tid & 1;
  const float* ag = A + (size_t)(tm * 128 + arow) * D_DIM + (size_t)kh * KH + ahalf * 16;
  __bf16* asw = &As[arow * 40 + ahalf * 16];

  // B staging: 8 chunks of 16 rows; wave w loads chunks 2w, 2w+1
  const int c0 = wid * 2, c1 = c0 + 1;
  const __bf16* bg0 = BT + (size_t)(tn * 128 + c0 * 16 + (lane >> 2)) * D_DIM + (size_t)kh * KH + (lane & 3) * 8;
  const __bf16* bg1 = BT + (size_t)(tn * 128 + c1 * 16 + (lane >> 2)) * D_DIM + (size_t)kh * KH + (lane & 3) * 8;
  __bf16* bl0 = &Bs[c0 * 16 * 32];
  __bf16* bl1 = &Bs[c1 * 16 * 32];

  const int fr = lane & 15;
  const int kq = (lane >> 4) * 8;
  f32x4 acc[4][4] = {};

  float4 pa[4];
  {
    const float4* ap = (const float4*)ag;
    pa[0] = ap[0]; pa[1] = ap[1]; pa[2] = ap[2]; pa[3] = ap[3];
  }

  for (int i = 0; i < ITERS; ++i) {
    const int k0 = i * 32;
    __syncthreads();                 // prev compute done; LDS reusable
    {                                // cvt + write A tile (padded rows)
      const float* pf = (const float*)pa;
      bf16x8 w0, w1;
#pragma unroll
      for (int j = 0; j < 8; ++j) { w0[j] = (__bf16)pf[j]; w1[j] = (__bf16)pf[j + 8]; }
      *(bf16x8*)asw       = w0;
      *(bf16x8*)(asw + 8) = w1;
    }
    gld_lds16(bg0 + k0, bl0);        // async B -> LDS
    gld_lds16(bg1 + k0, bl1);
    __syncthreads();                 // drains vmcnt+lgkm: As + Bs ready
    if (i != ITERS - 1) {            // prefetch next A; hides under MFMA block
      const float4* ap = (const float4*)(ag + k0 + 32);
      pa[0] = ap[0]; pa[1] = ap[1]; pa[2] = ap[2]; pa[3] = ap[3];
    }
    bf16x8 af[4], bf[4];
#pragma unroll
    for (int mi = 0; mi < 4; ++mi)
      af[mi] = *(const bf16x8*)&As[(wm * 64 + mi * 16 + fr) * 40 + kq];
#pragma unroll
    for (int ni = 0; ni < 4; ++ni)
      bf[ni] = *(const bf16x8*)&Bs[(wn * 64 + ni * 16 + fr) * 32 + kq];
#pragma unroll
    for (int mi = 0; mi < 4; ++mi)
#pragma unroll
      for (int ni = 0; ni < 4; ++ni)
        acc[mi][ni] = __builtin_amdgcn_mfma_f32_16x16x32_bf16(af[mi], bf[ni], acc[mi][ni], 0, 0, 0);
  }

  // store fp32 partials; D layout col=lane&15, row=(lane>>4)*4+reg [m89]
  float* Co = Cp + (size_t)kh * (M_DIM * H1P);
  const int row0 = tm * 128 + wm * 64 + ((lane >> 4) << 2);
  const int col0 = tn * 128 + wn * 64 + fr;
#pragma unroll
  for (int ni = 0; ni < 4; ++ni) {
    const int col = col0 + ni * 16;
#pragma unroll
    for (int mi = 0; mi < 4; ++mi)
#pragma unroll
      for (int r = 0; r < 4; ++r)
        Co[(size_t)(row0 + mi * 16 + r) * H1P + col] = acc[mi][ni][r];
  }
}

// ---- combine split-K halves + bias + relu -> h1 bf16 ----
__global__ __launch_bounds__(256) void k_reduce(const float* __restrict__ Cp,
                                                const float* __restrict__ b1,
                                                __bf16* __restrict__ h1) {
  const size_t i = ((size_t)blockIdx.x * 256 + threadIdx.x) * 4;  // grid 8192
  const f32x4 x = *(const f32x4*)(Cp + i);
  const f32x4 y = *(const f32x4*)(Cp + (size_t)M_DIM * H1P + i);
  const int col = (int)(i & (H1P - 1));
  bf16x4 o;
#pragma unroll
  for (int r = 0; r < 4; ++r) {
    const int c = col + r;
    const float b = (c < 1000) ? b1[c] : 0.f;
    o[r] = (__bf16)fmaxf(x[r] + y[r] + b, 0.f);
  }
  *(bf16x4*)(h1 + i) = o;
}

// ---- GEMM2 + logits fused, m-tile 32, grid 256 ----
// lg[m] = sigmoid(relu(h1 @ W2 + b2) @ W3 + b3)
__global__ __launch_bounds__(256) void k_gemm2l(const __bf16* __restrict__ h1,
                                                const __bf16* __restrict__ W2T,
                                                const float* __restrict__ b2,
                                                const float* __restrict__ W3,
                                                const float* __restrict__ b3,
                                                float* __restrict__ lg) {
  __shared__ __bf16 As[32 * 32];   // 2 KB: 2 chunks
  __shared__ __bf16 Bs[64 * 32];   // 4 KB: 4 chunks
  __shared__ float sred[32];
  const int tid  = threadIdx.x;
  const int lane = tid & 63;
  const int wid  = tid >> 6;
  const int bm   = blockIdx.x;
  const int wr = wid & 1, wn = wid >> 1;

  if (tid < 32) sred[tid] = 0.f;

  const int lr = lane >> 2;
  const int lc = (lane & 3) * 8;
  const __bf16* bgB = W2T + (size_t)(wid * 16 + lr) * H1P + lc;
  __bf16* blB = &Bs[wid * 16 * 32];
  const __bf16* bgA = h1 + (size_t)(bm * 32 + wid * 16 + lr) * H1P + lc;  // wid<2 only
  __bf16* blA = &As[wid * 16 * 32];

  const int fr = lane & 15;
  const int kq = (lane >> 4) * 8;
  f32x4 acc[2] = {};

  for (int i = 0; i < 32; ++i) {
    const int k0 = i * 32;
    __syncthreads();
    gld_lds16(bgB + k0, blB);
    if (wid < 2) gld_lds16(bgA + k0, blA);
    __syncthreads();
    const bf16x8 a = *(const bf16x8*)&As[(wr * 16 + fr) * 32 + kq];
#pragma unroll
    for (int ni = 0; ni < 2; ++ni) {
      const bf16x8 b = *(const bf16x8*)&Bs[(wn * 32 + ni * 16 + fr) * 32 + kq];
      acc[ni] = __builtin_amdgcn_mfma_f32_16x16x32_bf16(a, b, acc[ni], 0, 0, 0);
    }
  }
  // epilogue: lane covers j = wn*32 + ni*16 + fr, rows rl = wr*16 + quad*4 + r
  float s[4] = {0.f, 0.f, 0.f, 0.f};
#pragma unroll
  for (int ni = 0; ni < 2; ++ni) {
    const int j = wn * 32 + ni * 16 + fr;
    if (j < 40) {
      const float w3 = W3[j], bb = b2[j];
#pragma unroll
      for (int r = 0; r < 4; ++r)
        s[r] += fmaxf(acc[ni][r] + bb, 0.f) * w3;
    }
  }
#pragma unroll
  for (int off = 1; off < 16; off <<= 1)
#pragma unroll
    for (int r = 0; r < 4; ++r)
      s[r] += __shfl_xor(s[r], off, 16);
  if (fr == 0) {
    const int rl = wr * 16 + ((lane >> 4) << 2);
#pragma unroll
    for (int r = 0; r < 4; ++r)
      atomicAdd(&sred[rl + r], s[r]);
  }
  __syncthreads();
  if (tid < 32)
    lg[bm * 32 + tid] = 1.f / (1.f + __expf(-(sred[tid] + b3[0])));
}

// ---- ragged gather ----
__global__ void k_gather(const int* __restrict__ ts, const float* __restrict__ lg,
                         float* __restrict__ out) {
  const int t = blockIdx.x * 256 + threadIdx.x;
  const int b = t >> 9;
  const int s = ts[t];
  out[t] = (s > 0 && s < 512) ? lg[(b << 9) + s] : 0.f;
}

extern "C" void kernel_launch(void* const* d_in, const int* in_sizes, int n_in,
                              void* d_out, int out_size, void* d_ws, size_t ws_size,
                              hipStream_t stream) {
  const float* hs = (const float*)d_in[0];
  const int*   ts = (const int*)d_in[1];
  const float* W1 = (const float*)d_in[2];
  const float* b1 = (const float*)d_in[3];
  const float* W2 = (const float*)d_in[4];
  const float* b2 = (const float*)d_in[5];
  const float* W3 = (const float*)d_in[6];
  const float* b3 = (const float*)d_in[7];
  float* out = (float*)d_out;
  char* ws = (char*)d_ws;

  // layout (~105 MB; round 2 proved ws >= ~192 MB)
  float*  Cp  = (float*) (ws);                         // 2 * 8192*1024*4 = 67,108,864
  __bf16* W1T = (__bf16*)(ws + 67108864);              // 1024*9984*2     = 20,447,232
  __bf16* h1  = (__bf16*)(ws + 67108864 + 20447232);   // 8192*1024*2     = 16,777,216
  __bf16* W2T = (__bf16*)(ws + 67108864 + 20447232 + 16777216);            // 131,072
  float*  lg  = (float*) (ws + 67108864 + 20447232 + 16777216 + 131072);   //  32,768

  k_transpose_w1<<<dim3(312, 32), dim3(32, 8), 0, stream>>>(W1, W1T);
  k_prep_w2<<<256, 256, 0, stream>>>(W2, W2T);
  k_gemm1s<<<dim3(64, 8, 2), 256, 0, stream>>>(hs, W1T, Cp);
  k_reduce<<<8192, 256, 0, stream>>>(Cp, b1, h1);
  k_gemm2l<<<256, 256, 0, stream>>>(h1, W2T, b2, W3, b3, lg);
  k_gather<<<32, 256, 0, stream>>>(ts, lg, out);
}